// Round 1
// baseline (478.099 us; speedup 1.0000x reference)
//
#include <hip/hip_runtime.h>

// MovementPrunedLinear R4: prep rewritten for per-instruction coalescing
// (lane-contiguous float4 loads, wave-stride loop) + masked-W-block skip
// (in-kernel mask gating makes pre-zeroing redundant).
// mpl_main unchanged from R3 (243 us, known-good).

#define BM 128
#define BN 128
#define BK 64

typedef __attribute__((ext_vector_type(8))) short bf16x8;
typedef __attribute__((ext_vector_type(4))) float f32x4;

__device__ __forceinline__ unsigned short f2bf(float f) {
    union { float f; unsigned u; } v; v.f = f;
    return (unsigned short)((v.u + 0x7FFFu + ((v.u >> 16) & 1u)) >> 16);
}

#define THRESH (-2.1972245773362196f)   // logit(0.1)

// ---------------- merged pre-pass ----------------
// blocks [0,M): convert X row b. blocks [M,M+N): convert W row b-M, skipping
// masked 32-blocks (their Wb bytes are never consumed by mpl_main: staging is
// skipped when the 2-bit pair is 0, and MFMA is gated per 32-block bit).
// blocks [M+N, M+N+NB/4): pack mask bits, 4 nb per block (one per wave).
//
// Coalescing: lane i loads the contiguous float4 at element tid*4, looping
// with stride 1024 elements (= 256 threads * 4). Each load instruction is a
// contiguous 1 KiB wave segment; each ushort4 store a contiguous 512 B segment.
__global__ __launch_bounds__(256)
void prep(const float* __restrict__ X, const float* __restrict__ W,
          const float* __restrict__ scores,
          unsigned short* __restrict__ Xb, unsigned short* __restrict__ Wb,
          unsigned long long* __restrict__ mbits,
          int M, int N, int K) {
    const int b   = blockIdx.x;
    const int tid = threadIdx.x;
    const int KBlk = K >> 5;

    if (b < M) {
        // X row: dense convert
        const float* src = X + (long)b * K;
        unsigned short* dst = Xb + (long)b * K;
        for (int k = tid * 4; k < K; k += 1024) {
            const float4 a = *(const float4*)(src + k);
            ushort4 p;
            p.x = f2bf(a.x); p.y = f2bf(a.y); p.z = f2bf(a.z); p.w = f2bf(a.w);
            *(ushort4*)(dst + k) = p;
        }
    } else if (b < M + N) {
        // W row: convert only blocks that pass the mask (others never read)
        const int n = b - M;
        const float* src = W + (long)n * K;
        unsigned short* dst = Wb + (long)n * K;
        const float* srow = scores + (long)(n >> 5) * KBlk;
        for (int k = tid * 4; k < K; k += 1024) {
            if (srow[k >> 5] > THRESH) {          // uniform across 8-lane groups
                const float4 a = *(const float4*)(src + k);
                ushort4 p;
                p.x = f2bf(a.x); p.y = f2bf(a.y); p.z = f2bf(a.z); p.w = f2bf(a.w);
                *(ushort4*)(dst + k) = p;
            }
        }
    } else {
        // mask pack: requires KBlk == 128 (guarded in launcher)
        const int nb = (b - (M + N)) * 4 + (tid >> 6);
        const int l  = tid & 63;
        const unsigned long long b0 = __ballot(scores[(long)nb * KBlk + l] > THRESH);
        const unsigned long long b1 = __ballot(scores[(long)nb * KBlk + 64 + l] > THRESH);
        if (l == 0) { mbits[nb * 2] = b0; mbits[nb * 2 + 1] = b1; }
    }
}

// ---------------- main GEMM ----------------

__device__ __forceinline__ unsigned long long rfl64(unsigned long long v) {
    unsigned lo = __builtin_amdgcn_readfirstlane((unsigned)v);
    unsigned hi = __builtin_amdgcn_readfirstlane((unsigned)(v >> 32));
    return ((unsigned long long)hi << 32) | lo;
}

#define GLL16(g, l) __builtin_amdgcn_global_load_lds( \
    (const __attribute__((address_space(1))) void*)(g), \
    (__attribute__((address_space(3))) void*)(l), 16, 0, 0)

__global__ __launch_bounds__(256)
void mpl_main(const unsigned short* __restrict__ Xb,   // [M,K] bf16
              const unsigned short* __restrict__ Wb,   // [N,K] bf16 (masked blocks stale/unused)
              const float* __restrict__ bias,
              const unsigned long long* __restrict__ mb, // [N/32][2]
              float* __restrict__ out, int M, int N, int K)
{
    // Row = BK bf16 = 128 B = 8 chunks of 16 B. LDS slot (r, c') holds global
    // chunk c'^(r&7) (XOR swizzle via permuted global fetch; GLL dest is fixed).
    __shared__ unsigned short sA[BM * BK];   // 16 KB
    __shared__ unsigned short sB[BN * BK];   // 16 KB

    const int tid  = threadIdx.x;
    const int lane = tid & 63;
    const int wave = tid >> 6;
    const int m0   = blockIdx.y * BM;
    const int n0   = blockIdx.x * BN;
    const int wm   = (wave & 1) * 64;
    const int wn   = (wave >> 1) * 64;
    const long K2  = (long)K * 2;

    // per-nb mask words (scalarized)
    const int nbb = n0 >> 5;
    unsigned long long mlo[4], mhi[4];
#pragma unroll
    for (int i = 0; i < 4; i++) {
        mlo[i] = rfl64(mb[(nbb + i) * 2]);
        mhi[i] = rfl64(mb[(nbb + i) * 2 + 1]);
    }

    f32x4 acc[4][4];
#pragma unroll
    for (int i = 0; i < 4; i++)
#pragma unroll
        for (int j = 0; j < 4; j++)
            acc[i][j] = (f32x4){0.f, 0.f, 0.f, 0.f};

    // staging geometry: lane covers row (32i + tid>>3), swizzled chunk (tid&7)^((tid>>3)&7)
    const int r8   = tid >> 3;                               // 0..31
    const int cswz = ((tid & 7) ^ ((tid >> 3) & 7)) * 16;    // byte offset in row
    const char* gA = (const char*)Xb + (long)(m0 + r8) * K2 + cswz;
    const char* gB = (const char*)Wb + (long)(n0 + r8) * K2 + cswz;
    char* sAc = (char*)sA;
    char* sBc = (char*)sB;
    const int ldso = wave * 1024;

    // fragment geometry
    const int fr   = lane & 15;
    const int cxor = lane & 7;
    const int kqc  = lane >> 4;          // 0..3
    const int rowA = wm + fr;            // + mi*16
    const int rowB = wn + fr;            // + ni*16

    int kb2 = 0;
    for (int half = 0; half < 2; ++half) {
        const unsigned long long w0 = half ? mhi[0] : mlo[0];
        const unsigned long long w1 = half ? mhi[1] : mlo[1];
        const unsigned long long w2 = half ? mhi[2] : mlo[2];
        const unsigned long long w3 = half ? mhi[3] : mlo[3];
        for (int q = 0; q < 32; ++q, ++kb2) {
            const unsigned p0 = (unsigned)(w0 >> (2 * q)) & 3;
            const unsigned p1 = (unsigned)(w1 >> (2 * q)) & 3;
            const unsigned p2 = (unsigned)(w2 >> (2 * q)) & 3;
            const unsigned p3 = (unsigned)(w3 >> (2 * q)) & 3;
            if (!(p0 | p1 | p2 | p3)) continue;   // uniform across block

            const long ko = (long)kb2 * 128;
            // A staging: 4 instrs (rows 0..127)
#pragma unroll
            for (int i = 0; i < 4; i++)
                GLL16(gA + (long)i * 32 * K2 + ko, sAc + i * 4096 + ldso);
            // B staging: instr i == nb i; skip fully-masked pairs
            if (p0) GLL16(gB + 0L * 32 * K2 + ko, sBc + 0 * 4096 + ldso);
            if (p1) GLL16(gB + 1L * 32 * K2 + ko, sBc + 1 * 4096 + ldso);
            if (p2) GLL16(gB + 2L * 32 * K2 + ko, sBc + 2 * 4096 + ldso);
            if (p3) GLL16(gB + 3L * 32 * K2 + ko, sBc + 3 * 4096 + ldso);
            __syncthreads();

            const unsigned plo = (wave >> 1) ? p2 : p0;   // this wave's nb for ni 0,1
            const unsigned phi = (wave >> 1) ? p3 : p1;   // ni 2,3

#pragma unroll
            for (int kbl = 0; kbl < 2; ++kbl) {
                if (!(((plo | phi) >> kbl) & 1)) continue;
                const int boff = ((kqc | (kbl << 2)) ^ cxor) * 16;

                bf16x8 af[4];
#pragma unroll
                for (int mi = 0; mi < 4; mi++)
                    af[mi] = *(const bf16x8*)(sAc + (rowA + mi * 16) * 128 + boff);

                if ((plo >> kbl) & 1) {
                    const bf16x8 bf0 = *(const bf16x8*)(sBc + (rowB + 0)  * 128 + boff);
                    const bf16x8 bf1 = *(const bf16x8*)(sBc + (rowB + 16) * 128 + boff);
#pragma unroll
                    for (int mi = 0; mi < 4; mi++) {
                        acc[mi][0] = __builtin_amdgcn_mfma_f32_16x16x32_bf16(af[mi], bf0, acc[mi][0], 0, 0, 0);
                        acc[mi][1] = __builtin_amdgcn_mfma_f32_16x16x32_bf16(af[mi], bf1, acc[mi][1], 0, 0, 0);
                    }
                }
                if ((phi >> kbl) & 1) {
                    const bf16x8 bf2 = *(const bf16x8*)(sBc + (rowB + 32) * 128 + boff);
                    const bf16x8 bf3 = *(const bf16x8*)(sBc + (rowB + 48) * 128 + boff);
#pragma unroll
                    for (int mi = 0; mi < 4; mi++) {
                        acc[mi][2] = __builtin_amdgcn_mfma_f32_16x16x32_bf16(af[mi], bf2, acc[mi][2], 0, 0, 0);
                        acc[mi][3] = __builtin_amdgcn_mfma_f32_16x16x32_bf16(af[mi], bf3, acc[mi][3], 0, 0, 0);
                    }
                }
            }
            __syncthreads();
        }
    }

    // epilogue: C/D col=lane&15 (n), row=(lane>>4)*4+reg (m)
    const int cn = lane & 15;
    const int rq = (lane >> 4) * 4;
#pragma unroll
    for (int ni = 0; ni < 4; ni++) {
        const int n = n0 + wn + ni * 16 + cn;
        const float b = bias[n];
#pragma unroll
        for (int mi = 0; mi < 4; mi++) {
#pragma unroll
            for (int r = 0; r < 4; r++) {
                const int m = m0 + wm + mi * 16 + rq + r;
                out[(long)m * N + n] = acc[mi][ni][r] + b;
            }
        }
    }
}

// ---------------- fallback (R1 kernel) ----------------

#define FBK 32
#define LDSS (FBK + 8)
__global__ __launch_bounds__(256, 2)
void mpl_gemm_fb(const float* __restrict__ X, const float* __restrict__ W,
                 const float* __restrict__ bias, const float* __restrict__ scores,
                 float* __restrict__ out, int M, int N, int K)
{
    __shared__ unsigned short sA[BM * LDSS];
    __shared__ unsigned short sB[BN * LDSS];
    const int tid = threadIdx.x;
    const int m0 = blockIdx.y * BM, n0 = blockIdx.x * BN;
    const int wave = tid >> 6, lane = tid & 63;
    const int wm = (wave & 1) * 64, wn = (wave >> 1) * 64;
    const int kblocks = K >> 5;
    f32x4 acc[4][4];
#pragma unroll
    for (int i = 0; i < 4; i++)
#pragma unroll
        for (int j = 0; j < 4; j++) acc[i][j] = (f32x4){0.f,0.f,0.f,0.f};
    int srow[4], sc4[4], snb[4];
#pragma unroll
    for (int i = 0; i < 4; i++) {
        int f = tid + 256 * i;
        srow[i] = f >> 3; sc4[i] = f & 7; snb[i] = (n0 + srow[i]) >> 5;
    }
    for (int k0 = 0; k0 < K; k0 += FBK) {
        const int kb = k0 >> 5;
#pragma unroll
        for (int i = 0; i < 4; i++) {
            const float4 v = *(const float4*)(X + (long)(m0 + srow[i]) * K + k0 + sc4[i] * 4);
            ushort4 p; p.x = f2bf(v.x); p.y = f2bf(v.y); p.z = f2bf(v.z); p.w = f2bf(v.w);
            *(ushort4*)&sA[srow[i] * LDSS + sc4[i] * 4] = p;
        }
#pragma unroll
        for (int i = 0; i < 4; i++) {
            const float msk = (scores[snb[i] * kblocks + kb] > THRESH) ? 1.0f : 0.0f;
            const float4 v = *(const float4*)(W + (long)(n0 + srow[i]) * K + k0 + sc4[i] * 4);
            ushort4 p; p.x = f2bf(v.x*msk); p.y = f2bf(v.y*msk); p.z = f2bf(v.z*msk); p.w = f2bf(v.w*msk);
            *(ushort4*)&sB[srow[i] * LDSS + sc4[i] * 4] = p;
        }
        __syncthreads();
        const int fr = lane & 15, kq = (lane >> 4) * 8;
        bf16x8 af[4], bfr[4];
#pragma unroll
        for (int mi = 0; mi < 4; mi++) af[mi] = *(const bf16x8*)&sA[(wm + mi*16 + fr) * LDSS + kq];
#pragma unroll
        for (int ni = 0; ni < 4; ni++) bfr[ni] = *(const bf16x8*)&sB[(wn + ni*16 + fr) * LDSS + kq];
#pragma unroll
        for (int mi = 0; mi < 4; mi++)
#pragma unroll
            for (int ni = 0; ni < 4; ni++)
                acc[mi][ni] = __builtin_amdgcn_mfma_f32_16x16x32_bf16(af[mi], bfr[ni], acc[mi][ni], 0,0,0);
        __syncthreads();
    }
    const int cn = lane & 15, rq = (lane >> 4) * 4;
#pragma unroll
    for (int ni = 0; ni < 4; ni++) {
        const int n = n0 + wn + ni * 16 + cn;
        const float b = bias[n];
#pragma unroll
        for (int mi = 0; mi < 4; mi++)
#pragma unroll
            for (int r = 0; r < 4; r++)
                out[(long)(m0 + wm + mi*16 + rq + r) * N + n] = acc[mi][ni][r] + b;
    }
}

extern "C" void kernel_launch(void* const* d_in, const int* in_sizes, int n_in,
                              void* d_out, int out_size, void* d_ws, size_t ws_size,
                              hipStream_t stream) {
    const float* X      = (const float*)d_in[0];
    const float* W      = (const float*)d_in[1];
    const float* bias   = (const float*)d_in[2];
    const float* scores = (const float*)d_in[3];
    float* out          = (float*)d_out;

    const int N = in_sizes[2];            // 4096
    const int K = in_sizes[1] / N;        // 4096
    const int M = in_sizes[0] / K;        // 8192
    const int KB = K >> 5;                // 128
    const int NB = N >> 5;                // 128

    const size_t mk2 = (size_t)M * K * 2;
    const size_t nk2 = (size_t)N * K * 2;
    const size_t need = mk2 + nk2 + (size_t)NB * 16;

    if (ws_size >= need && KB == 128 && (M % 128) == 0 && (N % 128) == 0 &&
        (K % 1024) == 0 && (NB % 4) == 0) {
        unsigned short* Xb = (unsigned short*)d_ws;
        unsigned short* Wb = (unsigned short*)((char*)d_ws + mk2);
        unsigned long long* mbits = (unsigned long long*)((char*)d_ws + mk2 + nk2);

        prep<<<M + N + NB / 4, 256, 0, stream>>>(X, W, scores, Xb, Wb, mbits, M, N, K);

        dim3 grid(N / BN, M / BM);
        mpl_main<<<grid, dim3(256), 0, stream>>>(Xb, Wb, bias, mbits, out, M, N, K);
    } else {
        dim3 grid(N / BN, M / BM);
        mpl_gemm_fb<<<grid, dim3(256), 0, stream>>>(X, W, bias, scores, out, M, N, K);
    }
}